// Round 1
// baseline (378.313 us; speedup 1.0000x reference)
//
#include <hip/hip_runtime.h>

// WindowedNorm: 47x47 box-window mean/var normalization, zero-padded,
// count_include_pad=False, Bessel-corrected. NHWC fp32 [B,224,224,3].
//
// Fused single kernel:
//   Phase V: per-thread vertical 47-row running window sums (S, S^2) for
//            2-3 owned columns of one (batch, 8-row band); results for all
//            8 rows published to LDS as float2 (sum, sumsq), channel-
//            deinterleaved [r][c][w] with +1 padding.
//   Phase H: 384 tasks (8 rows x 3 ch x 16 segments of 14 cols); each task
//            slides a 47-tap horizontal window over the LDS vertical sums
//            (float2 b64 reads, ~5.4 reads/output), computes mean/var and
//            writes the normalized output.

namespace {
constexpr int H = 224;
constexpr int W = 224;
constexpr int C = 3;
constexpr int WC = W * C;            // 672
constexpr int RAD = 23;              // window = 47
constexpr int TH = 8;                // rows per block
constexpr int SEG = 14;              // output cols per horizontal task
constexpr int NSEG = W / SEG;        // 16
constexpr int PADW = W + 1;          // 225 float2 per (r,c) row
constexpr int NTASK = TH * C * NSEG; // 384
}

__global__ __launch_bounds__(256, 3) void wnorm_kernel(
    const float* __restrict__ in, float* __restrict__ out) {
  // 8 rows x 3 ch x 225 float2 = 43.2 KB -> 3 blocks/CU
  __shared__ float2 vsq[TH][C][PADW];

  const int tid = threadIdx.x;
  const int r0 = blockIdx.x * TH;
  const float* __restrict__ img = in + (size_t)blockIdx.y * H * WC;
  float* __restrict__ oimg = out + (size_t)blockIdx.y * H * WC;

  // ---- Phase V: vertical running window sums for owned columns ----
  // thread owns cols tid, tid+256, tid+512 (last only if < 672)
  const int ncol = (tid < WC - 512) ? 3 : 2;
  int wk[3], ck[3];
#pragma unroll
  for (int k = 0; k < 3; ++k) {
    int col = tid + (k << 8);
    wk[k] = col / 3;
    ck[k] = col - 3 * wk[k];
  }

  float S[3] = {0.f, 0.f, 0.f};
  float Q[3] = {0.f, 0.f, 0.f};
  {
    int lo = r0 - RAD; if (lo < 0) lo = 0;
    int hi = r0 + RAD; if (hi > H - 1) hi = H - 1;
    for (int r = lo; r <= hi; ++r) {
      const float* row = img + r * WC;
#pragma unroll
      for (int k = 0; k < 3; ++k)
        if (k < ncol) {
          float x = row[tid + (k << 8)];
          S[k] += x; Q[k] += x * x;
        }
    }
  }

  for (int r = 0; r < TH; ++r) {
    const int h = r0 + r;
#pragma unroll
    for (int k = 0; k < 3; ++k)
      if (k < ncol) vsq[r][ck[k]][wk[k]] = make_float2(S[k], Q[k]);

    const int ra = h + RAD + 1;   // row entering the window
    const int rs = h - RAD;       // row leaving the window
    if (ra < H) {
      const float* row = img + ra * WC;
#pragma unroll
      for (int k = 0; k < 3; ++k)
        if (k < ncol) { float x = row[tid + (k << 8)]; S[k] += x; Q[k] += x * x; }
    }
    if (rs >= 0) {
      const float* row = img + rs * WC;
#pragma unroll
      for (int k = 0; k < 3; ++k)
        if (k < ncol) { float x = row[tid + (k << 8)]; S[k] -= x; Q[k] -= x * x; }
    }
  }

  __syncthreads();

  // ---- Phase H: horizontal sliding windows + normalize + store ----
  for (int t = tid; t < NTASK; t += 256) {
    const int seg = t & (NSEG - 1);       // t % 16
    const int c = (t >> 4) % C;
    const int r = t / (NSEG * C);
    const int h = r0 + r;
    const int w0 = seg * SEG;

    float HS = 0.f, HQ = 0.f;
    {
      int wlo = w0 - RAD; if (wlo < 0) wlo = 0;
      int whi = w0 + RAD; if (whi > W - 1) whi = W - 1;
      for (int w = wlo; w <= whi; ++w) {
        float2 v = vsq[r][c][w];
        HS += v.x; HQ += v.y;
      }
    }
    const int chh = min(h + RAD, H - 1) - max(h - RAD, 0) + 1;
    const float* rowx = img + h * WC;
    float* rowo = oimg + h * WC;
#pragma unroll
    for (int i = 0; i < SEG; ++i) {
      const int w = w0 + i;
      const int cw = min(w + RAD, W - 1) - max(w - RAD, 0) + 1;
      const float n = (float)(chh * cw);
      const float inv = 1.0f / n;
      const float mean = HS * inv;
      const float sqm = HQ * inv;
      float var = (sqm - mean * mean) * (n / (n - 1.0f));
      var = fmaxf(var, 0.0f);
      const float x = rowx[w * 3 + c];
      rowo[w * 3 + c] = (x - mean) * rsqrtf(var + 1e-6f);
      // slide window one column right
      const int wa = w + RAD + 1;
      const int ws = w - RAD;
      if (wa < W)  { float2 v = vsq[r][c][wa]; HS += v.x; HQ += v.y; }
      if (ws >= 0) { float2 v = vsq[r][c][ws]; HS -= v.x; HQ -= v.y; }
    }
  }
}

extern "C" void kernel_launch(void* const* d_in, const int* in_sizes, int n_in,
                              void* d_out, int out_size, void* d_ws, size_t ws_size,
                              hipStream_t stream) {
  const float* in = (const float*)d_in[0];
  float* out = (float*)d_out;
  const int B = in_sizes[0] / (H * W * C);   // 128
  dim3 grid(H / TH, B);
  wnorm_kernel<<<grid, 256, 0, stream>>>(in, out);
}

// Round 2
// 342.463 us; speedup vs baseline: 1.1047x; 1.1047x over previous
//
#include <hip/hip_runtime.h>

// WindowedNorm: 47x47 box-window mean/var normalization, zero-padded,
// count_include_pad=False, Bessel-corrected. NHWC fp32 [B,224,224,3].
//
// Fused single kernel, one (batch, 7-row band) per block:
//   Phase V: per-thread vertical 47-row running window sums (S, Q=S^2) for
//            2-3 owned columns; per band row, publish float2(S,Q) to LDS,
//            channel-deinterleaved vsq[r*3+c][w].
//   Phase P: in-place inclusive prefix scan along w of each of the 21
//            (row,channel) LDS rows (wave shfl_up scan, 4 chunks of 64).
//   Phase N: linear element loop; window sum = P[w+23]-P[w-24] (2 LDS b64
//            reads), coalesced global re-read of x (L2-hot) + coalesced
//            store of (x-mean)*rsqrt(var+1e-6).

namespace {
constexpr int H = 224;
constexpr int W = 224;
constexpr int C = 3;
constexpr int WC = W * C;          // 672
constexpr int RAD = 23;            // window = 47
constexpr int TH = 7;              // rows per block (224/7 = 32 bands)
constexpr int PADW = W + 1;        // 225
constexpr int NROWS = TH * C;      // 21 scan rows
constexpr int NELEM = TH * WC;     // 4704 outputs per block
}

__global__ __launch_bounds__(256, 4) void wnorm_kernel(
    const float* __restrict__ in, float* __restrict__ out) {
  // 21 x 225 float2 = 37.8 KB -> 4 blocks/CU (16 waves/CU)
  __shared__ float2 vsq[NROWS][PADW];

  const int tid = threadIdx.x;
  const int lane = tid & 63;
  const int wv = tid >> 6;
  const int r0 = blockIdx.x * TH;
  const float* __restrict__ img = in + (size_t)blockIdx.y * (H * WC);
  float* __restrict__ oimg = out + (size_t)blockIdx.y * (H * WC);

  // ---- Phase V: vertical running window sums for owned columns ----
  // thread owns cols tid, tid+256, tid+512 (last only if < 672)
  const int ncol = (tid < WC - 512) ? 3 : 2;
  int wk[3], ck[3];
#pragma unroll
  for (int k = 0; k < 3; ++k) {
    int col = tid + (k << 8);
    wk[k] = col / 3;
    ck[k] = col - 3 * wk[k];
  }

  float S[3] = {0.f, 0.f, 0.f};
  float Q[3] = {0.f, 0.f, 0.f};
  {
    int lo = r0 - RAD; if (lo < 0) lo = 0;
    int hi = r0 + RAD; if (hi > H - 1) hi = H - 1;
    for (int r = lo; r <= hi; ++r) {
      const float* row = img + r * WC;
#pragma unroll
      for (int k = 0; k < 3; ++k)
        if (k < ncol) {
          float x = row[tid + (k << 8)];
          S[k] += x; Q[k] += x * x;
        }
    }
  }

  for (int r = 0; r < TH; ++r) {
#pragma unroll
    for (int k = 0; k < 3; ++k)
      if (k < ncol) vsq[r * C + ck[k]][wk[k]] = make_float2(S[k], Q[k]);

    const int ra = r0 + r + RAD + 1;   // row entering the window
    const int rs = r0 + r - RAD;       // row leaving the window
    if (ra < H) {
      const float* row = img + ra * WC;
#pragma unroll
      for (int k = 0; k < 3; ++k)
        if (k < ncol) { float x = row[tid + (k << 8)]; S[k] += x; Q[k] += x * x; }
    }
    if (rs >= 0) {
      const float* row = img + rs * WC;
#pragma unroll
      for (int k = 0; k < 3; ++k)
        if (k < ncol) { float x = row[tid + (k << 8)]; S[k] -= x; Q[k] -= x * x; }
    }
  }

  __syncthreads();

  // ---- Phase P: in-place inclusive prefix scan along w (per (r,c) row) ----
  for (int rr = wv; rr < NROWS; rr += 4) {
    float cx = 0.f, cy = 0.f;   // running carry across chunks
#pragma unroll
    for (int chunk = 0; chunk < 4; ++chunk) {
      const int w = (chunk << 6) + lane;
      const bool act = (w < W);
      float2 v = act ? vsq[rr][w] : make_float2(0.f, 0.f);
#pragma unroll
      for (int d = 1; d < 64; d <<= 1) {
        float sx = __shfl_up(v.x, d);
        float sy = __shfl_up(v.y, d);
        if (lane >= d) { v.x += sx; v.y += sy; }
      }
      v.x += cx; v.y += cy;
      if (act) vsq[rr][w] = v;
      cx = __shfl(v.x, 63);
      cy = __shfl(v.y, 63);
    }
  }

  __syncthreads();

  // ---- Phase N: coalesced normalize + store ----
  for (int idx = tid; idx < NELEM; idx += 256) {
    const int r = idx / WC;
    const int col = idx - r * WC;
    const int w = col / 3;
    const int c = col - 3 * w;
    const int h = r0 + r;

    const int hiw = min(w + RAD, W - 1);
    const int low = w - RAD - 1;               // exclusive left index
    const float2 Ph = vsq[r * C + c][hiw];
    const float2 Pl = (low >= 0) ? vsq[r * C + c][low] : make_float2(0.f, 0.f);
    const float HS = Ph.x - Pl.x;
    const float HQ = Ph.y - Pl.y;

    const int chh = min(h + RAD, H - 1) - max(h - RAD, 0) + 1;
    const int cww = hiw - max(w - RAD, 0) + 1;
    const float n = (float)(chh * cww);
    const float inv = 1.0f / n;
    const float mean = HS * inv;
    float var = (HQ * inv - mean * mean) * (n / (n - 1.0f));
    var = fmaxf(var, 0.0f);

    const float x = img[h * WC + col];
    oimg[h * WC + col] = (x - mean) * rsqrtf(var + 1e-6f);
  }
}

extern "C" void kernel_launch(void* const* d_in, const int* in_sizes, int n_in,
                              void* d_out, int out_size, void* d_ws, size_t ws_size,
                              hipStream_t stream) {
  const float* in = (const float*)d_in[0];
  float* out = (float*)d_out;
  const int B = in_sizes[0] / (H * W * C);   // 128
  dim3 grid(H / TH, B);                      // 32 x 128
  wnorm_kernel<<<grid, 256, 0, stream>>>(in, out);
}